// Round 3
// baseline (1082.507 us; speedup 1.0000x reference)
//
#include <hip/hip_runtime.h>
#include <hip/hip_fp16.h>
#include <math.h>

#define N_NODES 50000
#define E_EDGES 800000
#define E2 (E_EDGES + N_NODES)
#define HID 128
#define HEADS 4
#define OUTC 64
#define DEPTH 4
#define NEG_SLOPE 0.2f
#define LN_EPS 1e-6f

typedef float f32x4 __attribute__((ext_vector_type(4)));
typedef short short8 __attribute__((ext_vector_type(8)));

static __device__ inline unsigned short f2bf(float x) {
    unsigned int u = __float_as_uint(x);
    unsigned int r = (u + 0x7fffu + ((u >> 16) & 1u)) >> 16;
    return (unsigned short)r;
}
static __device__ inline float bf2f(unsigned short s) {
    return __uint_as_float(((unsigned int)s) << 16);
}

// ---------------- CSR build ----------------

__global__ void k_deg(const int* __restrict__ ei, int* __restrict__ deg) {
    int e = blockIdx.x * 256 + threadIdx.x;
    if (e >= E2) return;
    int d = (e < E_EDGES) ? ei[E_EDGES + e] : (e - E_EDGES);
    atomicAdd(&deg[d], 1);
}

__global__ void k_scan_block(const int* __restrict__ deg, int* __restrict__ partial,
                             int* __restrict__ bsum, int n) {
    __shared__ int sm[1024];
    int i = blockIdx.x * 1024 + threadIdx.x;
    int v = (i < n) ? deg[i] : 0;
    sm[threadIdx.x] = v;
    __syncthreads();
    for (int off = 1; off < 1024; off <<= 1) {
        int t = (threadIdx.x >= off) ? sm[threadIdx.x - off] : 0;
        __syncthreads();
        sm[threadIdx.x] += t;
        __syncthreads();
    }
    if (i < n) partial[i] = sm[threadIdx.x];
    if (threadIdx.x == 1023) bsum[blockIdx.x] = sm[1023];
}

__global__ void k_scan_bsum(int* __restrict__ bsum, int nb) {
    if (threadIdx.x == 0 && blockIdx.x == 0) {
        int run = 0;
        for (int b = 0; b < nb; ++b) { int v = bsum[b]; bsum[b] = run; run += v; }
    }
}

__global__ void k_scan_fix(const int* __restrict__ deg, int* __restrict__ row_ptr,
                           const int* __restrict__ bsum, int n) {
    int i = blockIdx.x * 1024 + threadIdx.x;
    if (i < n) row_ptr[i] = row_ptr[i] - deg[i] + bsum[blockIdx.x];
    if (i == 0) row_ptr[n] = E2;
}

__global__ void k_fill(const int* __restrict__ ei, const int* __restrict__ row_ptr,
                       int* __restrict__ cur, int* __restrict__ csr_src) {
    int e = blockIdx.x * 256 + threadIdx.x;
    if (e >= E2) return;
    int s, d;
    if (e < E_EDGES) { s = ei[e]; d = ei[E_EDGES + e]; } else { s = d = e - E_EDGES; }
    int pos = atomicAdd(&cur[d], 1);
    csr_src[row_ptr[d] + pos] = s;
}

// ---------------- input projection + LN (one wave per node) ----------------

__global__ __launch_bounds__(64) void k_in_proj_ln(const float* __restrict__ x,
                                                   const float* __restrict__ W,
                                                   const float* __restrict__ bias,
                                                   const float* __restrict__ gamma,
                                                   const float* __restrict__ beta,
                                                   float* __restrict__ h,
                                                   unsigned short* __restrict__ ln_hi,
                                                   unsigned short* __restrict__ ln_lo) {
    int nd = blockIdx.x, lane = threadIdx.x;
    const float* xr = x + nd * 3;
    float x0 = xr[0], x1 = xr[1], x2 = xr[2];
    int j0 = lane, j1 = lane + 64;
    float a = bias[j0] + x0 * W[j0] + x1 * W[HID + j0] + x2 * W[2 * HID + j0];
    float b = bias[j1] + x0 * W[j1] + x1 * W[HID + j1] + x2 * W[2 * HID + j1];
    size_t base = (size_t)nd * HID;
    h[base + j0] = a;
    h[base + j1] = b;
    float s = a + b;
    for (int o = 1; o < 64; o <<= 1) s += __shfl_xor(s, o);
    float mu = s * (1.0f / 128.0f);
    float da = a - mu, db = b - mu;
    float v = da * da + db * db;
    for (int o = 1; o < 64; o <<= 1) v += __shfl_xor(v, o);
    float rstd = rsqrtf(v * (1.0f / 128.0f) + LN_EPS);
    float va = da * rstd * gamma[j0] + beta[j0];
    float vb = db * rstd * gamma[j1] + beta[j1];
    unsigned short ha = f2bf(va), hb = f2bf(vb);
    ln_hi[base + j0] = ha;
    ln_hi[base + j1] = hb;
    ln_lo[base + j0] = f2bf(va - bf2f(ha));
    ln_lo[base + j1] = f2bf(vb - bf2f(hb));
}

// ---------------- repack W_conv into MFMA B-fragment layout (hi/lo bf16) ----------------
// Bp[layer][ntile(32)][kc(4)][lane(64)][j(8)]; k = kc*32 + (lane>>4)*8 + j, n = ntile*16 + (lane&15)

__global__ void k_repackB(const float* __restrict__ W_conv,
                          unsigned short* __restrict__ Bp_hi,
                          unsigned short* __restrict__ Bp_lo) {
    int idx = blockIdx.x * 256 + threadIdx.x;
    if (idx >= DEPTH * 65536) return;
    int j     = idx & 7;
    int lane  = (idx >> 3) & 63;
    int kc    = (idx >> 9) & 3;
    int ntile = (idx >> 11) & 31;
    int layer = idx >> 16;
    int k = kc * 32 + (lane >> 4) * 8 + j;
    int n = ntile * 16 + (lane & 15);
    float w = W_conv[(size_t)layer * 65536 + (size_t)k * 512 + n];
    unsigned short hi = f2bf(w);
    Bp_hi[idx] = hi;
    Bp_lo[idx] = f2bf(w - bf2f(hi));
}

// ---------------- MFMA GEMM + fused alpha dots ----------------
// one wave per 64x64 C tile; no LDS. bf16x3: Ahi*Bhi + Ahi*Blo + Alo*Bhi.
// by in [0,8): head = by>>1, col half = by&1. Alpha partials -> atomicAdd into as_/ad_ (zeroed).

__global__ __launch_bounds__(64) void k_gemm_mfma(const unsigned short* __restrict__ ln_hi,
                                                  const unsigned short* __restrict__ ln_lo,
                                                  const unsigned short* __restrict__ Bp_hi,
                                                  const unsigned short* __restrict__ Bp_lo,
                                                  const float* __restrict__ att_s,
                                                  const float* __restrict__ att_d,
                                                  __half* __restrict__ xh,
                                                  float* __restrict__ as_,
                                                  float* __restrict__ ad_) {
    int lane = threadIdx.x;
    int row0 = blockIdx.x * 64;
    int by   = blockIdx.y;           // col block of 64 (4 ntiles)
    int quad = lane >> 4;
    int l15  = lane & 15;
    int hh   = by >> 1;
    int half = by & 1;

    float attS[4], attD[4];
    for (int nt = 0; nt < 4; ++nt) {
        int c = hh * HID + half * 64 + nt * 16 + l15;
        attS[nt] = att_s[c];
        attD[nt] = att_d[c];
    }

    f32x4 acc[4][4];
    for (int mt = 0; mt < 4; ++mt)
        for (int nt = 0; nt < 4; ++nt)
            acc[mt][nt] = (f32x4)(0.0f);

    for (int kc = 0; kc < 4; ++kc) {
        short8 ah[4], al[4], bh[4], bl[4];
        for (int mt = 0; mt < 4; ++mt) {
            int row = row0 + mt * 16 + l15;
            if (row >= N_NODES) row = N_NODES - 1;   // clamp; stores guarded
            size_t off = (size_t)row * 128 + kc * 32 + quad * 8;
            ah[mt] = *(const short8*)(ln_hi + off);
            al[mt] = *(const short8*)(ln_lo + off);
        }
        for (int nt = 0; nt < 4; ++nt) {
            size_t off = ((size_t)((by * 4 + nt) * 4 + kc) * 64 + lane) * 8;
            bh[nt] = *(const short8*)(Bp_hi + off);
            bl[nt] = *(const short8*)(Bp_lo + off);
        }
        for (int mt = 0; mt < 4; ++mt)
            for (int nt = 0; nt < 4; ++nt) {
                acc[mt][nt] = __builtin_amdgcn_mfma_f32_16x16x32_bf16(ah[mt], bh[nt], acc[mt][nt], 0, 0, 0);
                acc[mt][nt] = __builtin_amdgcn_mfma_f32_16x16x32_bf16(ah[mt], bl[nt], acc[mt][nt], 0, 0, 0);
                acc[mt][nt] = __builtin_amdgcn_mfma_f32_16x16x32_bf16(al[mt], bh[nt], acc[mt][nt], 0, 0, 0);
            }
    }

    // C/D layout: col = l15 + nt*16 + by*64, row = mt*16 + quad*4 + r
    int col0 = by * 64;
    for (int mt = 0; mt < 4; ++mt) {
        for (int r = 0; r < 4; ++r) {
            int row = row0 + mt * 16 + quad * 4 + r;
            // xh store
            if (row < N_NODES) {
                __half* dst = xh + (size_t)row * 512 + col0 + l15;
                for (int nt = 0; nt < 4; ++nt)
                    dst[nt * 16] = __float2half(acc[mt][nt][r]);
            }
            // alpha partials: reduce over the 64 cols of this tile
            float ps = 0.f, pd = 0.f;
            for (int nt = 0; nt < 4; ++nt) {
                float c = acc[mt][nt][r];
                ps += c * attS[nt];
                pd += c * attD[nt];
            }
            for (int o = 1; o < 16; o <<= 1) {
                ps += __shfl_xor(ps, o);
                pd += __shfl_xor(pd, o);
            }
            if (l15 == 0 && row < N_NODES) {
                atomicAdd(&as_[row * HEADS + hh], ps);
                atomicAdd(&ad_[row * HEADS + hh], pd);
            }
        }
    }
}

// ---------------- per-node softmax-aggregate + mean + bias + relu + residual + next-LN ----------------
// No max pass: e = leaky_relu(as+ad) is bounded (~|e|<4), exp(e) is safe in fp32 and
// softmax is shift-invariant, so the result matches the reference bit-for-nearly.

__global__ __launch_bounds__(64) void k_agg(const __half* __restrict__ xh,
                                            const float* __restrict__ as_,
                                            const float* __restrict__ ad_,
                                            const int* __restrict__ row_ptr,
                                            const int* __restrict__ csr_src,
                                            const float* __restrict__ bias,
                                            float* __restrict__ h,
                                            unsigned short* __restrict__ ln_hi,
                                            unsigned short* __restrict__ ln_lo,
                                            const float* __restrict__ gamma,
                                            const float* __restrict__ beta,
                                            int write_ln) {
    int nd = blockIdx.x, lane = threadIdx.x;
    int start = row_ptr[nd], end = row_ptr[nd + 1];
    int hh = lane >> 4;
    float adh = ad_[nd * HEADS + hh];

    float acc[8] = {0, 0, 0, 0, 0, 0, 0, 0};
    float z = 0.f;
    const __half* xbase = xh + (size_t)lane * 8;

    int e = start;
    for (; e + 2 <= end; e += 2) {
        int s0 = csr_src[e], s1 = csr_src[e + 1];
        float v0 = as_[s0 * HEADS + hh] + adh;
        float v1 = as_[s1 * HEADS + hh] + adh;
        v0 = (v0 >= 0.f) ? v0 : NEG_SLOPE * v0;
        v1 = (v1 >= 0.f) ? v1 : NEG_SLOPE * v1;
        float p0 = __expf(v0), p1 = __expf(v1);
        z += p0 + p1;
        union { float4 f4; __half hv[8]; } u0, u1;
        u0.f4 = *(const float4*)(xbase + (size_t)s0 * 512);
        u1.f4 = *(const float4*)(xbase + (size_t)s1 * 512);
        for (int j = 0; j < 8; ++j)
            acc[j] += p0 * __half2float(u0.hv[j]) + p1 * __half2float(u1.hv[j]);
    }
    if (e < end) {
        int s0 = csr_src[e];
        float v0 = as_[s0 * HEADS + hh] + adh;
        v0 = (v0 >= 0.f) ? v0 : NEG_SLOPE * v0;
        float p0 = __expf(v0);
        z += p0;
        union { float4 f4; __half hv[8]; } u0;
        u0.f4 = *(const float4*)(xbase + (size_t)s0 * 512);
        for (int j = 0; j < 8; ++j)
            acc[j] += p0 * __half2float(u0.hv[j]);
    }

    float inv = 1.0f / z;
    for (int j = 0; j < 8; ++j) acc[j] *= inv;
    for (int j = 0; j < 8; ++j) acc[j] += __shfl_xor(acc[j], 16);
    for (int j = 0; j < 8; ++j) acc[j] += __shfl_xor(acc[j], 32);

    if (lane < 16) {
        int c = lane * 8;
        float* hr = h + (size_t)nd * HID + c;
        const float* br = bias + c;
        float r[8];
        for (int j = 0; j < 8; ++j) {
            float t = 0.25f * acc[j] + br[j];
            t = fmaxf(t, 0.f);
            r[j] = t + hr[j];
        }
        *(float4*)(hr)     = make_float4(r[0], r[1], r[2], r[3]);
        *(float4*)(hr + 4) = make_float4(r[4], r[5], r[6], r[7]);

        if (write_ln) {
            // LayerNorm over the 128-ch row spread across lanes 0..15 (8 ch each)
            float s = 0.f;
            for (int j = 0; j < 8; ++j) s += r[j];
            for (int o = 1; o < 16; o <<= 1) s += __shfl_xor(s, o);
            float mu = s * (1.0f / 128.0f);
            float var = 0.f;
            for (int j = 0; j < 8; ++j) { float d = r[j] - mu; var += d * d; }
            for (int o = 1; o < 16; o <<= 1) var += __shfl_xor(var, o);
            float rstd = rsqrtf(var * (1.0f / 128.0f) + LN_EPS);
            short8 vhi, vlo;
            for (int j = 0; j < 8; ++j) {
                float lv = (r[j] - mu) * rstd * gamma[c + j] + beta[c + j];
                unsigned short hi = f2bf(lv);
                vhi[j] = (short)hi;
                vlo[j] = (short)f2bf(lv - bf2f(hi));
            }
            *(short8*)(ln_hi + (size_t)nd * HID + c) = vhi;
            *(short8*)(ln_lo + (size_t)nd * HID + c) = vlo;
        }
    }
}

// ---------------- output projection ----------------

__global__ __launch_bounds__(64) void k_out_proj(const float* __restrict__ h,
                                                 const float* __restrict__ W,
                                                 const float* __restrict__ b,
                                                 float* __restrict__ out) {
    int n = blockIdx.x, j = threadIdx.x;
    const float* hr = h + (size_t)n * HID;
    float acc = b[j];
    for (int k = 0; k < HID; ++k) acc += hr[k] * W[k * OUTC + j];
    out[(size_t)n * OUTC + j] = acc;
}

// ---------------- launch ----------------

extern "C" void kernel_launch(void* const* d_in, const int* in_sizes, int n_in,
                              void* d_out, int out_size, void* d_ws, size_t ws_size,
                              hipStream_t stream) {
    const float* x       = (const float*)d_in[0];
    const int*   ei      = (const int*)d_in[1];
    const float* W_in    = (const float*)d_in[2];
    const float* b_in    = (const float*)d_in[3];
    const float* W_conv  = (const float*)d_in[4];
    const float* att_src = (const float*)d_in[5];
    const float* att_dst = (const float*)d_in[6];
    const float* b_conv  = (const float*)d_in[7];
    const float* ln_g    = (const float*)d_in[8];
    const float* ln_b    = (const float*)d_in[9];
    const float* W_out   = (const float*)d_in[10];
    const float* b_out   = (const float*)d_in[11];
    float* out = (float*)d_out;

    char* ws = (char*)d_ws;
    size_t off = 0;
    auto alloc = [&](size_t bytes) { void* p = ws + off; off = (off + bytes + 255) & ~(size_t)255; return p; };
    float* h            = (float*)alloc((size_t)N_NODES * HID * 4);
    unsigned short* lhi = (unsigned short*)alloc((size_t)N_NODES * HID * 2);
    unsigned short* llo = (unsigned short*)alloc((size_t)N_NODES * HID * 2);
    __half* xh          = (__half*)alloc((size_t)N_NODES * 512 * 2);
    float* as_          = (float*)alloc((size_t)N_NODES * HEADS * 4);   // contiguous with ad_
    float* ad_          = (float*)alloc((size_t)N_NODES * HEADS * 4);
    unsigned short* Bph = (unsigned short*)alloc((size_t)DEPTH * 65536 * 2);
    unsigned short* Bpl = (unsigned short*)alloc((size_t)DEPTH * 65536 * 2);
    int* deg    = (int*)alloc((size_t)N_NODES * 4);
    int* cur    = (int*)alloc((size_t)N_NODES * 4);
    int* row_ptr= (int*)alloc((size_t)(N_NODES + 1) * 4);
    int* csr    = (int*)alloc((size_t)E2 * 4);
    int* bsum   = (int*)alloc(256 * 4);
    (void)ws_size; (void)n_in; (void)in_sizes; (void)out_size;

    hipMemsetAsync(deg, 0, (size_t)N_NODES * 4, stream);
    hipMemsetAsync(cur, 0, (size_t)N_NODES * 4, stream);

    // CSR build
    k_deg<<<(E2 + 255) / 256, 256, 0, stream>>>(ei, deg);
    int nb = (N_NODES + 1023) / 1024;
    k_scan_block<<<nb, 1024, 0, stream>>>(deg, row_ptr, bsum, N_NODES);
    k_scan_bsum<<<1, 64, 0, stream>>>(bsum, nb);
    k_scan_fix<<<nb, 1024, 0, stream>>>(deg, row_ptr, bsum, N_NODES);
    k_fill<<<(E2 + 255) / 256, 256, 0, stream>>>(ei, row_ptr, cur, csr);

    // weight repack (per call; graph-safe)
    k_repackB<<<(DEPTH * 65536 + 255) / 256, 256, 0, stream>>>(W_conv, Bph, Bpl);

    // input projection + first LN
    k_in_proj_ln<<<N_NODES, 64, 0, stream>>>(x, W_in, b_in, ln_g, ln_b, h, lhi, llo);

    // layers
    for (int i = 0; i < DEPTH; ++i) {
        const float* asp = att_src + (size_t)i * HEADS * HID;
        const float* adp = att_dst + (size_t)i * HEADS * HID;
        const float* bcp = b_conv + (size_t)i * HID;
        int write_ln = (i + 1 < DEPTH) ? 1 : 0;
        const float* gp = ln_g + (size_t)(i + 1 < DEPTH ? i + 1 : i) * HID;
        const float* bp = ln_b + (size_t)(i + 1 < DEPTH ? i + 1 : i) * HID;

        // zero alpha accumulators (as_ and ad_ are contiguous)
        hipMemsetAsync(as_, 0, (size_t)N_NODES * HEADS * 4 * 2, stream);

        dim3 gg((N_NODES + 63) / 64, 8);
        k_gemm_mfma<<<gg, 64, 0, stream>>>(lhi, llo, Bph + (size_t)i * 65536,
                                           Bpl + (size_t)i * 65536, asp, adp,
                                           xh, as_, ad_);
        k_agg<<<N_NODES, 64, 0, stream>>>(xh, as_, ad_, row_ptr, csr, bcp, h,
                                          lhi, llo, gp, bp, write_ln);
    }

    k_out_proj<<<N_NODES, 64, 0, stream>>>(h, W_out, b_out, out);
}